// Round 5
// baseline (316.528 us; speedup 1.0000x reference)
//
#include <hip/hip_runtime.h>

#define NC 8192
#define NT 4096
#define NLAGS 103
#define WS_STRIDE 104
#define XBASE (NC*NLAGS)

// ---------------- Kernel 1: per-channel cross-correlation ----------------
// One block (4 waves) per channel. d1s (zero-padded d1) and d2 in LDS.
// LDS granule = 16 B. Layout transform within 128-granule (2 KB) slabs:
//   q = 128s + 8a + b (a<16, b<8)  ->  phys = 128s + 16b + a
// All compute reads are at granule q = 8*lane + (wave-uniform c), which maps
// to 16-consecutive-granule phys runs == canonical conflict-free b128 reads.
// BOTH buffers are whole slabs (D1GR, D2GR multiples of 128) so the
// permutation is bijective inside each buffer (round-4 bug: 8.5 slabs let
// pad granules escape the buffer).
// d2 is DMA'd via global_load_lds with Pinv-permuted per-lane SOURCE (linear
// dest, zero VGPR); d1 is reg-staged with phys-linear lane-consecutive
// ds_write_b128 (pads written as zeros in the same pass).
// Lag base -1: wave wv covers L = 28*wv + l - 1 (l=0..27), valid 0..102.
// d1s logical dword for (k,L) = k + L + 1; left pad 52, right pad 60.
__device__ __forceinline__ int Pg(int q) {     // logical -> phys granule
    return (q & ~127) | ((q & 7) << 4) | ((q >> 3) & 15);
}
__device__ __forceinline__ int Pinv(int p) {   // phys -> logical granule
    return (p & ~127) | ((p & 15) << 3) | ((p >> 4) & 7);
}

#define D1GR 1152        // 9 full slabs (needs 1052 logical; 18 KB)
#define D2GR 1024        // 8 full slabs (16 KB)
#define SMEMDW ((D1GR + D2GR)*4)   // 8704 dwords = 34.8 KB -> 4 blocks/CU
#define REDS 29          // reduction row stride (odd: conflict-free)

__global__ __launch_bounds__(256, 4)
void xcorr_kernel(const float* __restrict__ g1, const float* __restrict__ g2,
                  float* __restrict__ ws) {
    __shared__ __align__(128) float smem[SMEMDW];
    char* d1b = (char*)smem;
    char* d2b = (char*)smem + D1GR*16;
    const int tid  = threadIdx.x;
    const int wv   = tid >> 6;
    const int lane = tid & 63;
    const int c    = blockIdx.x;
    const float* g1c = g1 + (size_t)c * NT;
    const float* g2c = g2 + (size_t)c * NT;

    // ---- d2 -> LDS: async DMA, Pinv-permuted per-lane source ----
    // dest granule p = 64*j + lane (linear); holds logical granule Pinv(p).
    #pragma unroll
    for (int t = 0; t < 4; ++t) {
        const int j = 4*wv + t;                  // 16 instrs over 4 waves
        const int q = Pinv(64*j + lane);
        __builtin_amdgcn_global_load_lds(
            (const float*)((const char*)g2c + 16*q),
            (float*)(d2b + 1024*j),              // wave-uniform base
            16, 0, 0);
    }

    // ---- d1s -> LDS: reg-staged, phys-linear lane-consecutive writes ----
    // phys granule p holds logical granule Pinv(p); logical granules
    // [13,1037) are data (g1 byte 16*q-208), the rest are zero pads.
    #pragma unroll
    for (int t = 0; t < 5; ++t) {
        const int p = tid + 256*t;
        if (p < D1GR) {
            const int q = Pinv(p);
            float4 v = make_float4(0.f, 0.f, 0.f, 0.f);
            if (q >= 13 && q < 1037)
                v = *(const float4*)((const char*)g1c + 16*q - 208);
            *(float4*)(d1b + 16*p) = v;
        }
    }
    __syncthreads();   // drains vmcnt (DMA + gathers) and lgkm (ds writes)

    float acc[28];
    #pragma unroll
    for (int l = 0; l < 28; ++l) acc[l] = 0.f;

    // acc[l] = R[28*wv + l - 1]; lane owns k in [32*lane, +32) per it
    #pragma unroll 1
    for (int it = 0; it < 2; ++it) {
        const int qb = 512*it + 8*lane;          // d2 granule base (k0/4)
        const int qa = qb + 7*wv;                // d1s window granule base
        #pragma unroll
        for (int h = 0; h < 2; ++h) {            // j-halves: live set ~105
            float b[16];                         // d2[k0+16h .. +15]
            #pragma unroll
            for (int t = 0; t < 4; ++t) {
                float4 v = *(const float4*)(d2b + 16*Pg(qb + 4*h + t));
                b[4*t]=v.x; b[4*t+1]=v.y; b[4*t+2]=v.z; b[4*t+3]=v.w;
            }
            float w[44];                         // d1s[k0+16h+28wv .. +43]
            #pragma unroll
            for (int t = 0; t < 11; ++t) {
                float4 v = *(const float4*)(d1b + 16*Pg(qa + 4*h + t));
                w[4*t]=v.x; w[4*t+1]=v.y; w[4*t+2]=v.z; w[4*t+3]=v.w;
            }
            #pragma unroll
            for (int j = 0; j < 16; ++j)
                #pragma unroll
                for (int l = 0; l < 28; ++l)
                    acc[l] = fmaf(w[l+j], b[j], acc[l]);
            __builtin_amdgcn_sched_barrier(0);   // cap liveness: don't merge halves
        }
    }

    // ---- cross-lane reduction; reuse dead d2 buffer as scratch ----
    __syncthreads();                             // all compute reads done
    #pragma unroll
    for (int l = 0; l < 28; ++l) acc[l] += __shfl_down(acc[l], 32);
    float* red = (float*)d2b + wv * (32*REDS);   // 4*928 = 3712 <= 4096
    if (lane < 32) {
        #pragma unroll
        for (int l = 0; l < 28; ++l) red[lane*REDS + l] = acc[l];
    }
    // same-wave DS ordering: no barrier needed before read-back
    if (lane < 28) {
        float s = 0.f;
        #pragma unroll
        for (int r = 0; r < 32; ++r) s += red[r*REDS + lane];
        const int L = 28*wv + lane - 1;
        if (L >= 0 && L < NLAGS) ws[(size_t)c * WS_STRIDE + L] = s;
    }
}

// -------- Kernel 2: moving average across channels + pick max|R| --------
#define TS 112   // tile stride (16*7: rows alias 2-way = free)
__global__ __launch_bounds__(256, 4)
void ma_pick_kernel(const float* __restrict__ ws, float* __restrict__ out) {
    __shared__ float tile[52*TS];
    __shared__ float matile[32*TS];
    const int tid = threadIdx.x;
    const int c0  = blockIdx.x * 32;

    for (int i = tid; i < 52*TS; i += 256) {
        int r   = i / TS;
        int col = i - r*TS;
        int g   = c0 - 10 + r;
        float v = 0.f;
        if (g >= 0 && g < NC && col < NLAGS) v = ws[(size_t)g*WS_STRIDE + col];
        tile[i] = v;
    }
    __syncthreads();

    {   // rolling 20-channel window sum; thread = one lag, 16 channels
        const int l = tid & 127;
        const int h = tid >> 7;
        if (l < NLAGS) {
            const int cc0 = h * 16;
            float s = 0.f;
            #pragma unroll
            for (int r = 0; r < 20; ++r) s += tile[(cc0 + r)*TS + l];
            #pragma unroll 1
            for (int cc = cc0; cc < cc0 + 16; ++cc) {
                float ma = s / 20.0f;
                matile[cc*TS + l] = ma;
                out[(size_t)(c0 + cc)*NLAGS + l] = ma;   // coalesced across l
                s += tile[(cc + 20)*TS + l] - tile[cc*TS + l];
            }
        }
    }
    __syncthreads();

    // per-channel argmax|R| (first-index tie-break), max, min
    const int wv = tid >> 6, lane = tid & 63;
    #pragma unroll 1
    for (int s8 = 0; s8 < 8; ++s8) {
        const int cc = wv*8 + s8;
        float v1 = matile[cc*TS + lane];
        float a1 = fabsf(v1);
        int   i1 = lane;
        float vmx = v1, vmn = v1;
        if (lane < NLAGS - 64) {                 // second element: l = lane+64
            float v2 = matile[cc*TS + 64 + lane];
            float a2 = fabsf(v2);
            vmx = fmaxf(vmx, v2); vmn = fminf(vmn, v2);
            if (a2 > a1) { a1 = a2; i1 = 64 + lane; v1 = v2; }
        }
        #pragma unroll
        for (int d = 32; d >= 1; d >>= 1) {
            float oa  = __shfl_xor(a1, d);
            int   oi  = __shfl_xor(i1, d);
            float ov  = __shfl_xor(v1, d);
            float omx = __shfl_xor(vmx, d);
            float omn = __shfl_xor(vmn, d);
            vmx = fmaxf(vmx, omx);
            vmn = fminf(vmn, omn);
            if (oa > a1 || (oa == a1 && oi < i1)) { a1 = oa; i1 = oi; v1 = ov; }
        }
        if (lane == 0) {
            const int ch = c0 + cc;
            out[XBASE + ch]        = v1;                         // vmain
            out[XBASE + NC + ch]   = (v1 >= 0.f) ? vmn : vmx;    // vside
            out[XBASE + 2*NC + ch] = (float)(i1 - 51) * 0.01f;   // tmax
        }
    }
}

extern "C" void kernel_launch(void* const* d_in, const int* in_sizes, int n_in,
                              void* d_out, int out_size, void* d_ws, size_t ws_size,
                              hipStream_t stream) {
    const float* g1 = (const float*)d_in[0];
    const float* g2 = (const float*)d_in[1];
    float* out = (float*)d_out;
    float* ws  = (float*)d_ws;   // 8192*104*4 = 3.4 MB scratch

    hipLaunchKernelGGL(xcorr_kernel, dim3(NC), dim3(256), 0, stream, g1, g2, ws);
    hipLaunchKernelGGL(ma_pick_kernel, dim3(NC/32), dim3(256), 0, stream, ws, out);
}